// Round 2
// baseline (805.748 us; speedup 1.0000x reference)
//
#include <hip/hip_runtime.h>
#include <hip/hip_bf16.h>

#define D_MODEL 1024
#define N_HEAD  16
#define HD      64
#define T_SEQ   2048
#define B_SZ    4
#define M_ROWS  (B_SZ * T_SEQ)   // 8192

typedef __bf16 bf16;
typedef __bf16 bf16x4 __attribute__((ext_vector_type(4)));
typedef __bf16 bf16x8 __attribute__((ext_vector_type(8)));
typedef float  floatx4 __attribute__((ext_vector_type(4)));

__device__ __forceinline__ floatx4 fzero4() {
    floatx4 z = {0.f, 0.f, 0.f, 0.f};
    return z;
}

// async global->LDS, 16B per lane. LDS dest = wave-uniform base + lane*16.
__device__ __forceinline__ void async_ld16(void* g, void* l) {
    __builtin_amdgcn_global_load_lds(
        (__attribute__((address_space(1))) void*)g,
        (__attribute__((address_space(3))) void*)l,
        16, 0, 0);
}

// fp32 -> bf16 convert, 8 elems/thread, grid-stride
__global__ __launch_bounds__(256) void cvt_kernel(
    const float* __restrict__ src, bf16* __restrict__ dst, int n8)
{
    int i = blockIdx.x * blockDim.x + threadIdx.x;
    int stride = gridDim.x * blockDim.x;
    for (; i < n8; i += stride) {
        float4 a = ((const float4*)src)[2 * i];
        float4 b = ((const float4*)src)[2 * i + 1];
        bf16x8 o;
        o[0] = (bf16)a.x; o[1] = (bf16)a.y; o[2] = (bf16)a.z; o[3] = (bf16)a.w;
        o[4] = (bf16)b.x; o[5] = (bf16)b.y; o[6] = (bf16)b.z; o[7] = (bf16)b.w;
        ((bf16x8*)dst)[i] = o;
    }
}

// C[8192,1024] = A[8192,1024](bf16) @ W^T(bf16 [N,K]) + bias(fp32).
// OMODE: 0 = bf16 head-split [B,H,T,64]; 1 = bf16 head-split transposed [B,H,64,T];
//        2 = fp32 row-major [M,N]
template <int OMODE>
__global__ __launch_bounds__(256) void gemm_bf16(
    const bf16* __restrict__ A, const bf16* __restrict__ W,
    const float* __restrict__ bias, void* __restrict__ Out)
{
    __shared__ bf16 ldsA[128 * 64];   // no pad (global_load_lds linear layout)
    __shared__ bf16 ldsW[128 * 64];

    const int tid  = threadIdx.x;
    const int wave = tid >> 6, lane = tid & 63;
    const int quad = lane >> 4, l15 = lane & 15;
    const int wr = wave >> 1, wc = wave & 1;
    const int m0 = blockIdx.y * 128, n0 = blockIdx.x * 128;

    floatx4 acc[4][4];
#pragma unroll
    for (int i = 0; i < 4; ++i)
#pragma unroll
        for (int j = 0; j < 4; ++j) acc[i][j] = fzero4();

    // per-lane global base: wave w stages rows w*32..w*32+31; lane i -> row lane>>3, 16B chunk lane&7
    const bf16* gA = A + (size_t)(m0 + wave * 32 + (lane >> 3)) * 1024 + (lane & 7) * 8;
    const bf16* gW = W + (size_t)(n0 + wave * 32 + (lane >> 3)) * 1024 + (lane & 7) * 8;

    for (int kt = 0; kt < 16; ++kt) {
        __syncthreads();   // all waves done reading LDS from prev iter
#pragma unroll
        for (int j = 0; j < 4; ++j)
            async_ld16((void*)(gA + kt * 64 + j * 8 * 1024), &ldsA[(wave * 32 + j * 8) * 64]);
#pragma unroll
        for (int j = 0; j < 4; ++j)
            async_ld16((void*)(gW + kt * 64 + j * 8 * 1024), &ldsW[(wave * 32 + j * 8) * 64]);
        __syncthreads();   // drains vmcnt -> staging visible

#pragma unroll
        for (int ks = 0; ks < 2; ++ks) {
            bf16x8 af[4], bw[4];
#pragma unroll
            for (int i = 0; i < 4; ++i)
                af[i] = *(const bf16x8*)(&ldsA[(wr * 64 + i * 16 + l15) * 64 + ks * 32 + quad * 8]);
#pragma unroll
            for (int j = 0; j < 4; ++j)
                bw[j] = *(const bf16x8*)(&ldsW[(wc * 64 + j * 16 + l15) * 64 + ks * 32 + quad * 8]);
#pragma unroll
            for (int i = 0; i < 4; ++i)
#pragma unroll
                for (int j = 0; j < 4; ++j)
                    acc[i][j] = __builtin_amdgcn_mfma_f32_16x16x32_bf16(af[i], bw[j], acc[i][j], 0, 0, 0);
        }
    }

#pragma unroll
    for (int i = 0; i < 4; ++i) {
#pragma unroll
        for (int j = 0; j < 4; ++j) {
#pragma unroll
            for (int r = 0; r < 4; ++r) {
                int m = m0 + wr * 64 + i * 16 + quad * 4 + r;
                int n = n0 + wc * 64 + j * 16 + l15;
                float val = acc[i][j][r] + bias[n];
                if (OMODE == 2) {
                    ((float*)Out)[(size_t)m * 1024 + n] = val;
                } else {
                    int b = m >> 11, t = m & 2047;
                    int h = n >> 6,  d = n & 63;
                    size_t addr;
                    if (OMODE == 0)
                        addr = ((size_t)(b * N_HEAD + h) * T_SEQ + t) * HD + d;
                    else
                        addr = ((size_t)(b * N_HEAD + h) * HD + d) * T_SEQ + t;
                    ((bf16*)Out)[addr] = (bf16)val;
                }
            }
        }
    }
}

// Flash-style causal attention.
// Qh, Kh: [B,H,T,64] bf16.  Vt: [B,H,64,T] bf16.  AO: [B,T,D] bf16.
// grid (16 q-tiles, 64 bh), block 256 (4 waves x 32 q-rows).
__global__ __launch_bounds__(256) void attn_kernel(
    const bf16* __restrict__ Qh, const bf16* __restrict__ Kh,
    const bf16* __restrict__ Vt, bf16* __restrict__ AO)
{
    __shared__ bf16 Ks[128 * 64];    // 16 KB, no pad (global_load_lds)
    __shared__ bf16 Ps[128 * 136];   // 34.8 KB, own buffer -> wave-local round trip

    const int tid  = threadIdx.x;
    const int wave = tid >> 6, lane = tid & 63;
    const int quad = lane >> 4, l15 = lane & 15;
    const int qt = blockIdx.x, bh = blockIdx.y;
    const size_t base = (size_t)bh * T_SEQ * HD;

    // Q fragments direct from global (A-operand layout)
    bf16x8 qf[2][2];
    const bf16* qbase = Qh + base + (size_t)(qt * 128 + wave * 32) * HD;
#pragma unroll
    for (int ti = 0; ti < 2; ++ti)
#pragma unroll
        for (int ks = 0; ks < 2; ++ks)
            qf[ti][ks] = *(const bf16x8*)(qbase + (ti * 16 + l15) * HD + ks * 32 + quad * 8);

    const float scale2 = 0.125f * 1.44269504088896340736f;  // 1/sqrt(64) * log2(e)
    float mrow[2][4], lrow[2][4];
    floatx4 oacc[2][4];
#pragma unroll
    for (int ti = 0; ti < 2; ++ti) {
#pragma unroll
        for (int r = 0; r < 4; ++r) { mrow[ti][r] = -1e30f; lrow[ti][r] = 0.f; }
#pragma unroll
        for (int nj = 0; nj < 4; ++nj) oacc[ti][nj] = fzero4();
    }

    const bf16* kg = Kh + base + (size_t)(wave * 32 + (lane >> 3)) * HD + (lane & 7) * 8;
    const bf16* vg = Vt + base + (size_t)(l15)*T_SEQ + quad * 8;

    for (int kt = 0; kt <= qt; ++kt) {
        __syncthreads();   // all waves done reading Ks from prev iter
#pragma unroll
        for (int j = 0; j < 4; ++j)
            async_ld16((void*)(kg + (size_t)(kt * 128 + j * 8) * HD), &Ks[(wave * 32 + j * 8) * 64]);
        __syncthreads();   // staging visible

        // S = Q K^T
        floatx4 sacc[2][8];
#pragma unroll
        for (int ti = 0; ti < 2; ++ti)
#pragma unroll
            for (int tj = 0; tj < 8; ++tj) sacc[ti][tj] = fzero4();
#pragma unroll
        for (int ks = 0; ks < 2; ++ks) {
#pragma unroll
            for (int tj = 0; tj < 8; ++tj) {
                bf16x8 kf = *(const bf16x8*)(&Ks[(tj * 16 + l15) * 64 + ks * 32 + quad * 8]);
                sacc[0][tj] = __builtin_amdgcn_mfma_f32_16x16x32_bf16(qf[0][ks], kf, sacc[0][tj], 0, 0, 0);
                sacc[1][tj] = __builtin_amdgcn_mfma_f32_16x16x32_bf16(qf[1][ks], kf, sacc[1][tj], 0, 0, 0);
            }
        }

        // online softmax
        const bool diag = (kt == qt);
#pragma unroll
        for (int ti = 0; ti < 2; ++ti) {
#pragma unroll
            for (int r = 0; r < 4; ++r) {
                int qrow = wave * 32 + ti * 16 + quad * 4 + r;
                float sv[8];
                float mx = -1e30f;
#pragma unroll
                for (int tj = 0; tj < 8; ++tj) {
                    float s = sacc[ti][tj][r] * scale2;
                    if (diag && (tj * 16 + l15) > qrow) s = -1e30f;
                    sv[tj] = s;
                    mx = fmaxf(mx, s);
                }
#pragma unroll
                for (int off = 1; off < 16; off <<= 1)
                    mx = fmaxf(mx, __shfl_xor(mx, off));
                float mnew  = fmaxf(mrow[ti][r], mx);
                float alpha = exp2f(mrow[ti][r] - mnew);
                float rsum  = 0.f;
#pragma unroll
                for (int tj = 0; tj < 8; ++tj) {
                    float p = exp2f(sv[tj] - mnew);
                    sacc[ti][tj][r] = p;
                    rsum += p;
                }
#pragma unroll
                for (int off = 1; off < 16; off <<= 1)
                    rsum += __shfl_xor(rsum, off);
                lrow[ti][r] = lrow[ti][r] * alpha + rsum;
                mrow[ti][r] = mnew;
#pragma unroll
                for (int nj = 0; nj < 4; ++nj)
                    oacc[ti][nj][r] *= alpha;
            }
        }

        // P -> LDS (wave-local rows; no barrier needed, lgkmcnt dep only)
#pragma unroll
        for (int ti = 0; ti < 2; ++ti)
#pragma unroll
            for (int tj = 0; tj < 8; ++tj)
#pragma unroll
                for (int r = 0; r < 4; ++r)
                    Ps[(wave * 32 + ti * 16 + quad * 4 + r) * 136 + tj * 16 + l15] =
                        (bf16)sacc[ti][tj][r];

        // O += P V   (V fragments direct from global; B-operand layout)
#pragma unroll
        for (int ks = 0; ks < 4; ++ks) {
            bf16x8 pf[2];
            pf[0] = *(const bf16x8*)(&Ps[(wave * 32 + l15) * 136 + ks * 32 + quad * 8]);
            pf[1] = *(const bf16x8*)(&Ps[(wave * 32 + 16 + l15) * 136 + ks * 32 + quad * 8]);
#pragma unroll
            for (int nj = 0; nj < 4; ++nj) {
                bf16x8 vf = *(const bf16x8*)(vg + (size_t)(nj * 16) * T_SEQ + kt * 128 + ks * 32);
                oacc[0][nj] = __builtin_amdgcn_mfma_f32_16x16x32_bf16(pf[0], vf, oacc[0][nj], 0, 0, 0);
                oacc[1][nj] = __builtin_amdgcn_mfma_f32_16x16x32_bf16(pf[1], vf, oacc[1][nj], 0, 0, 0);
            }
        }
    }

    // epilogue: O /= l, store to AO [B,T,D]
    const int b = bh >> 4, h = bh & 15;
#pragma unroll
    for (int ti = 0; ti < 2; ++ti) {
#pragma unroll
        for (int r = 0; r < 4; ++r) {
            float rl = 1.f / lrow[ti][r];
            int qrow = qt * 128 + wave * 32 + ti * 16 + quad * 4 + r;
#pragma unroll
            for (int nj = 0; nj < 4; ++nj) {
                int d = nj * 16 + l15;
                AO[((size_t)(b * T_SEQ + qrow)) * D_MODEL + h * HD + d] =
                    (bf16)(oacc[ti][nj][r] * rl);
            }
        }
    }
}

extern "C" void kernel_launch(void* const* d_in, const int* in_sizes, int n_in,
                              void* d_out, int out_size, void* d_ws, size_t ws_size,
                              hipStream_t stream)
{
    const float* q  = (const float*)d_in[0];
    const float* k  = (const float*)d_in[1];
    const float* v  = (const float*)d_in[2];
    const float* wq = (const float*)d_in[3];
    const float* bq = (const float*)d_in[4];
    const float* wk = (const float*)d_in[5];
    const float* bk = (const float*)d_in[6];
    const float* wv = (const float*)d_in[7];
    const float* bv = (const float*)d_in[8];
    const float* wo = (const float*)d_in[9];
    const float* bo = (const float*)d_in[10];

    char* ws = (char*)d_ws;
    char* dob = (char*)d_out;
    const size_t SZ = (size_t)M_ROWS * D_MODEL * sizeof(bf16);  // 16 MiB

    // region time-multiplexing (ws = 64 MB, d_out doubles as 32 MB scratch):
    bf16* Qb  = (bf16*)(dob);            // converted q            (dies after Q-GEMM)
    bf16* Kb  = (bf16*)(dob + SZ);       // converted k            (dies after K-GEMM)
    bf16* Vb  = (bf16*)(ws);             // converted v            (dies after V-GEMM)
    bf16* AO  = (bf16*)(ws);             // attn out               (after Vb dead)
    bf16* Qh  = (bf16*)(ws + SZ);        // Q heads                (dies after attn)
    bf16* Wob = (bf16*)(ws + SZ);        // wo bf16                (after Qh dead)
    bf16* Wqb = (bf16*)(ws + 2 * SZ);    // wq bf16                (dies after Q-GEMM)
    bf16* Kh  = (bf16*)(ws + 2 * SZ);    // K heads                (after Wqb dead)
    bf16* Wkb = (bf16*)(ws + 3 * SZ);    // wk bf16                (dies after K-GEMM)
    bf16* Vt  = (bf16*)(ws + 3 * SZ);    // V heads transposed     (after Wkb dead)
    bf16* Wvb = (bf16*)(dob);            // wv bf16                (after Qb dead)

    const int NQ8 = M_ROWS * D_MODEL / 8;   // 1M
    const int NW8 = D_MODEL * D_MODEL / 8;  // 128K
    dim3 cb(256);
    dim3 gg(8, 64), gb(256);

    hipLaunchKernelGGL(cvt_kernel, dim3(4096), cb, 0, stream, q, Qb, NQ8);
    hipLaunchKernelGGL(cvt_kernel, dim3(512),  cb, 0, stream, wq, Wqb, NW8);
    hipLaunchKernelGGL((gemm_bf16<0>), gg, gb, 0, stream, Qb, Wqb, bq, (void*)Qh);

    hipLaunchKernelGGL(cvt_kernel, dim3(4096), cb, 0, stream, k, Kb, NQ8);
    hipLaunchKernelGGL(cvt_kernel, dim3(512),  cb, 0, stream, wk, Wkb, NW8);
    hipLaunchKernelGGL((gemm_bf16<0>), gg, gb, 0, stream, Kb, Wkb, bk, (void*)Kh);

    hipLaunchKernelGGL(cvt_kernel, dim3(4096), cb, 0, stream, v, Vb, NQ8);
    hipLaunchKernelGGL(cvt_kernel, dim3(512),  cb, 0, stream, wv, Wvb, NW8);
    hipLaunchKernelGGL((gemm_bf16<1>), gg, gb, 0, stream, Vb, Wvb, bv, (void*)Vt);

    hipLaunchKernelGGL(attn_kernel, dim3(16, 64), gb, 0, stream, Qh, Kh, Vt, AO);

    hipLaunchKernelGGL(cvt_kernel, dim3(512),  cb, 0, stream, wo, Wob, NW8);
    hipLaunchKernelGGL((gemm_bf16<2>), gg, gb, 0, stream, AO, Wob, bo, d_out);
}

// Round 3
// 536.815 us; speedup vs baseline: 1.5010x; 1.5010x over previous
//
#include <hip/hip_runtime.h>
#include <hip/hip_bf16.h>

#define D_MODEL 1024
#define N_HEAD  16
#define HD      64
#define T_SEQ   2048
#define B_SZ    4
#define M_ROWS  (B_SZ * T_SEQ)   // 8192

typedef __bf16 bf16;
typedef __bf16 bf16x4 __attribute__((ext_vector_type(4)));
typedef __bf16 bf16x8 __attribute__((ext_vector_type(8)));
typedef float  floatx4 __attribute__((ext_vector_type(4)));

__device__ __forceinline__ floatx4 fzero4() {
    floatx4 z = {0.f, 0.f, 0.f, 0.f};
    return z;
}

// async global->LDS, 16B/lane. LDS dest = wave-uniform base + lane*16.
__device__ __forceinline__ void async_ld16(const void* g, void* l) {
    __builtin_amdgcn_global_load_lds(
        (const __attribute__((address_space(1))) void*)g,
        (__attribute__((address_space(3))) void*)l,
        16, 0, 0);
}

// fused fp32 -> bf16 convert: up to 4 segments selected by blockIdx.y
__global__ __launch_bounds__(256) void cvt4_kernel(
    const float* s0, bf16* d0, int n0,
    const float* s1, bf16* d1, int n1,
    const float* s2, bf16* d2, int n2,
    const float* s3, bf16* d3, int n3)
{
    const float* src; bf16* dst; int n8;
    switch (blockIdx.y) {
        case 0:  src = s0; dst = d0; n8 = n0; break;
        case 1:  src = s1; dst = d1; n8 = n1; break;
        case 2:  src = s2; dst = d2; n8 = n2; break;
        default: src = s3; dst = d3; n8 = n3; break;
    }
    int i = blockIdx.x * blockDim.x + threadIdx.x;
    int stride = gridDim.x * blockDim.x;
    for (; i < n8; i += stride) {
        float4 a = ((const float4*)src)[2 * i];
        float4 b = ((const float4*)src)[2 * i + 1];
        bf16x8 o;
        o[0] = (bf16)a.x; o[1] = (bf16)a.y; o[2] = (bf16)a.z; o[3] = (bf16)a.w;
        o[4] = (bf16)b.x; o[5] = (bf16)b.y; o[6] = (bf16)b.z; o[7] = (bf16)b.w;
        ((bf16x8*)dst)[i] = o;
    }
}

// C[8192,1024] = A(bf16) @ W^T(bf16 [N,K]) + bias(fp32).
// OMODE: 0 = bf16 head-split [B,H,T,64]; 1 = bf16 [B,H,64,T] (V); 2 = fp32 [M,N]
// Fused-pair variant: blockIdx.z in [0,ZN) selects the (A,W,bias,Out) tuple.
template <int OMODE>
__global__ __launch_bounds__(256) void gemm_bf16(
    const bf16* __restrict__ A0, const bf16* __restrict__ W0,
    const float* __restrict__ b0v, void* __restrict__ O0,
    const bf16* __restrict__ A1, const bf16* __restrict__ W1,
    const float* __restrict__ b1v, void* __restrict__ O1)
{
    __shared__ bf16 ldsA[128 * 64];
    __shared__ bf16 ldsW[128 * 64];

    const bf16* A    = blockIdx.z ? A1 : A0;
    const bf16* W    = blockIdx.z ? W1 : W0;
    const float* bias = blockIdx.z ? b1v : b0v;
    void* Out        = blockIdx.z ? O1 : O0;

    const int tid  = threadIdx.x;
    const int wave = tid >> 6, lane = tid & 63;
    const int quad = lane >> 4, l15 = lane & 15;
    const int wr = wave >> 1, wc = wave & 1;
    const int m0 = blockIdx.y * 128, n0 = blockIdx.x * 128;

    floatx4 acc[4][4];
#pragma unroll
    for (int i = 0; i < 4; ++i)
#pragma unroll
        for (int j = 0; j < 4; ++j) acc[i][j] = fzero4();

    const bf16* gA = A + (size_t)(m0 + wave * 32 + (lane >> 3)) * 1024 + (lane & 7) * 8;
    const bf16* gW = W + (size_t)(n0 + wave * 32 + (lane >> 3)) * 1024 + (lane & 7) * 8;

    for (int kt = 0; kt < 16; ++kt) {
        __syncthreads();
#pragma unroll
        for (int j = 0; j < 4; ++j)
            async_ld16((const void*)(gA + kt * 64 + j * 8 * 1024), &ldsA[(wave * 32 + j * 8) * 64]);
#pragma unroll
        for (int j = 0; j < 4; ++j)
            async_ld16((const void*)(gW + kt * 64 + j * 8 * 1024), &ldsW[(wave * 32 + j * 8) * 64]);
        __syncthreads();

#pragma unroll
        for (int ks = 0; ks < 2; ++ks) {
            bf16x8 af[4], bw[4];
#pragma unroll
            for (int i = 0; i < 4; ++i)
                af[i] = *(const bf16x8*)(&ldsA[(wr * 64 + i * 16 + l15) * 64 + ks * 32 + quad * 8]);
#pragma unroll
            for (int j = 0; j < 4; ++j)
                bw[j] = *(const bf16x8*)(&ldsW[(wc * 64 + j * 16 + l15) * 64 + ks * 32 + quad * 8]);
#pragma unroll
            for (int i = 0; i < 4; ++i)
#pragma unroll
                for (int j = 0; j < 4; ++j)
                    acc[i][j] = __builtin_amdgcn_mfma_f32_16x16x32_bf16(af[i], bw[j], acc[i][j], 0, 0, 0);
        }
    }

#pragma unroll
    for (int i = 0; i < 4; ++i) {
#pragma unroll
        for (int j = 0; j < 4; ++j) {
#pragma unroll
            for (int r = 0; r < 4; ++r) {
                int m = m0 + wr * 64 + i * 16 + quad * 4 + r;
                int n = n0 + wc * 64 + j * 16 + l15;
                float val = acc[i][j][r] + bias[n];
                if (OMODE == 2) {
                    ((float*)Out)[(size_t)m * 1024 + n] = val;
                } else {
                    int b = m >> 11, t = m & 2047;
                    int h = n >> 6,  d = n & 63;
                    size_t addr;
                    if (OMODE == 0)
                        addr = ((size_t)(b * N_HEAD + h) * T_SEQ + t) * HD + d;
                    else
                        addr = ((size_t)(b * N_HEAD + h) * HD + d) * T_SEQ + t;
                    ((bf16*)Out)[addr] = (bf16)val;
                }
            }
        }
    }
}

// Flash-style causal attention, S^T formulation.
// Qh, Kh: [B,H,T,64] bf16.  Vt: [B,H,64,T] bf16.  AO: [B,T,D] bf16.
// grid (16 q-tiles, 64 bh), block 256 (4 waves x 32 q-rows).
// blockIdx.x -> qt = 15 - blockIdx.x (longest blocks dispatch first).
__global__ __launch_bounds__(256) void attn_kernel(
    const bf16* __restrict__ Qh, const bf16* __restrict__ Kh,
    const bf16* __restrict__ Vt, bf16* __restrict__ AO)
{
    __shared__ bf16 Ks[128 * 64];     // 16 KB (global_load_lds, linear)
    __shared__ bf16 Vts[64 * 128];    // 16 KB (global_load_lds, XOR-swizzled chunks)
    __shared__ bf16 Ps[128 * 136];    // 34.8 KB, wave-local P round-trip

    const int tid  = threadIdx.x;
    const int wave = tid >> 6, lane = tid & 63;
    const int quad = lane >> 4, l15 = lane & 15;
    const int qt = 15 - blockIdx.x, bh = blockIdx.y;
    const size_t base = (size_t)bh * T_SEQ * HD;

    // Q fragments, B-operand layout: lane l15 = q-index, k-dim = quad*8+j
    bf16x8 qf[2][2];
    const bf16* qbase = Qh + base + (size_t)(qt * 128 + wave * 32) * HD;
#pragma unroll
    for (int ti = 0; ti < 2; ++ti)
#pragma unroll
        for (int ks = 0; ks < 2; ++ks)
            qf[ti][ks] = *(const bf16x8*)(qbase + (ti * 16 + l15) * HD + ks * 32 + quad * 8);

    const float scale2 = 0.125f * 1.44269504088896340736f;  // 1/sqrt(64) * log2(e)
    float mrow[2] = {-1e30f, -1e30f}, lrow[2] = {0.f, 0.f};
    floatx4 oacc[2][4];
#pragma unroll
    for (int ti = 0; ti < 2; ++ti)
#pragma unroll
        for (int nj = 0; nj < 4; ++nj) oacc[ti][nj] = fzero4();

    // staging bases
    const bf16* kg = Kh + base + (size_t)(wave * 32 + (lane >> 3)) * HD + (lane & 7) * 8;
    // V: row d = wave*16 + j*4 + (lane>>4); fetch global chunk (lane&15)^(d&15)
    const int vrow_lo = (lane >> 4);            // 0..3
    const int vchunk  = (lane & 15);

    for (int kt = 0; kt <= qt; ++kt) {
        __syncthreads();   // all waves done reading Ks/Vts from prev iter
#pragma unroll
        for (int j = 0; j < 4; ++j)
            async_ld16((const void*)(kg + (size_t)(kt * 128 + j * 8) * HD),
                       &Ks[(wave * 32 + j * 8) * 64]);
#pragma unroll
        for (int j = 0; j < 4; ++j) {
            int d = wave * 16 + j * 4 + vrow_lo;
            int gc = vchunk ^ (d & 15);
            async_ld16((const void*)(Vt + base + (size_t)d * T_SEQ + kt * 128 + gc * 8),
                       &Vts[(wave * 16 + j * 4) * 128]);
        }
        __syncthreads();   // staging visible

        // S^T = K Q^T : A = K-frag (l15 = k-row), B = Q-frag (l15 = q-col)
        floatx4 sacc[2][8];
#pragma unroll
        for (int ti = 0; ti < 2; ++ti)
#pragma unroll
            for (int tj = 0; tj < 8; ++tj) sacc[ti][tj] = fzero4();
#pragma unroll
        for (int ks = 0; ks < 2; ++ks) {
#pragma unroll
            for (int tj = 0; tj < 8; ++tj) {
                bf16x8 kf = *(const bf16x8*)(&Ks[(tj * 16 + l15) * 64 + ks * 32 + quad * 8]);
                sacc[0][tj] = __builtin_amdgcn_mfma_f32_16x16x32_bf16(kf, qf[0][ks], sacc[0][tj], 0, 0, 0);
                sacc[1][tj] = __builtin_amdgcn_mfma_f32_16x16x32_bf16(kf, qf[1][ks], sacc[1][tj], 0, 0, 0);
            }
        }

        // online softmax on S^T: lane owns one q (= l15) per ti; k spread over tj,quad,r
        const bool diag = (kt == qt);
#pragma unroll
        for (int ti = 0; ti < 2; ++ti) {
            const int ql = wave * 32 + ti * 16 + l15;
            float mx = -1e30f;
#pragma unroll
            for (int tj = 0; tj < 8; ++tj) {
#pragma unroll
                for (int r = 0; r < 4; ++r) {
                    float s = sacc[ti][tj][r] * scale2;
                    if (diag && (tj * 16 + quad * 4 + r) > ql) s = -1e30f;
                    sacc[ti][tj][r] = s;
                    mx = fmaxf(mx, s);
                }
            }
            mx = fmaxf(mx, __shfl_xor(mx, 16));
            mx = fmaxf(mx, __shfl_xor(mx, 32));
            float mnew  = fmaxf(mrow[ti], mx);
            float alpha = exp2f(mrow[ti] - mnew);
            float rsum  = 0.f;
#pragma unroll
            for (int tj = 0; tj < 8; ++tj) {
                bf16x4 pv;
#pragma unroll
                for (int r = 0; r < 4; ++r) {
                    float p = exp2f(sacc[ti][tj][r] - mnew);
                    rsum += p;
                    pv[r] = (bf16)p;
                }
                // P row-major: row q = ql, cols tj*16+quad*4 .. +3  (b64 write)
                *(bf16x4*)(&Ps[ql * 136 + tj * 16 + quad * 4]) = pv;
            }
            rsum += __shfl_xor(rsum, 16);
            rsum += __shfl_xor(rsum, 32);
            lrow[ti] = lrow[ti] * alpha + rsum;
            mrow[ti] = mnew;
            // rescale O rows: oacc row index = quad*4+r; alpha lives at lane l15 = that row
#pragma unroll
            for (int r = 0; r < 4; ++r) {
                float ar = __shfl(alpha, quad * 4 + r);
#pragma unroll
                for (int nj = 0; nj < 4; ++nj)
                    oacc[ti][nj][r] *= ar;
            }
        }

        // O += P V : A = P from LDS (lane l15 = q-row), B = V^T swizzled frags
#pragma unroll
        for (int ks = 0; ks < 4; ++ks) {
            bf16x8 pf[2];
            pf[0] = *(const bf16x8*)(&Ps[(wave * 32 + l15) * 136 + ks * 32 + quad * 8]);
            pf[1] = *(const bf16x8*)(&Ps[(wave * 32 + 16 + l15) * 136 + ks * 32 + quad * 8]);
#pragma unroll
            for (int nj = 0; nj < 4; ++nj) {
                int pos = (ks * 4 + quad) ^ l15;   // XOR-swizzled chunk position
                bf16x8 vf = *(const bf16x8*)(&Vts[(nj * 16 + l15) * 128 + pos * 8]);
                oacc[0][nj] = __builtin_amdgcn_mfma_f32_16x16x32_bf16(pf[0], vf, oacc[0][nj], 0, 0, 0);
                oacc[1][nj] = __builtin_amdgcn_mfma_f32_16x16x32_bf16(pf[1], vf, oacc[1][nj], 0, 0, 0);
            }
        }
    }

    // epilogue: O /= l ; O rows = quad*4+r, cols d = nj*16+l15
    const int b = bh >> 4, h = bh & 15;
#pragma unroll
    for (int ti = 0; ti < 2; ++ti) {
        float lr = __shfl(lrow[ti], quad * 4 + 0);  // placeholder; per-r below
#pragma unroll
        for (int r = 0; r < 4; ++r) {
            float lv = __shfl(lrow[ti], quad * 4 + r);
            float rl = 1.f / lv;
            int qrow = qt * 128 + wave * 32 + ti * 16 + quad * 4 + r;
#pragma unroll
            for (int nj = 0; nj < 4; ++nj) {
                int d = nj * 16 + l15;
                AO[((size_t)(b * T_SEQ + qrow)) * D_MODEL + h * HD + d] =
                    (bf16)(oacc[ti][nj][r] * rl);
            }
        }
        (void)lr;
    }
}

extern "C" void kernel_launch(void* const* d_in, const int* in_sizes, int n_in,
                              void* d_out, int out_size, void* d_ws, size_t ws_size,
                              hipStream_t stream)
{
    const float* q  = (const float*)d_in[0];
    const float* k  = (const float*)d_in[1];
    const float* v  = (const float*)d_in[2];
    const float* wq = (const float*)d_in[3];
    const float* bq = (const float*)d_in[4];
    const float* wk = (const float*)d_in[5];
    const float* bk = (const float*)d_in[6];
    const float* wv = (const float*)d_in[7];
    const float* bv = (const float*)d_in[8];
    const float* wo = (const float*)d_in[9];
    const float* bo = (const float*)d_in[10];

    char* ws  = (char*)d_ws;
    char* dob = (char*)d_out;
    const size_t SZ = (size_t)M_ROWS * D_MODEL * sizeof(bf16);  // 16 MiB
    const size_t WSZ = (size_t)D_MODEL * D_MODEL * sizeof(bf16); // 2 MiB

    // Region lifetimes:
    // ws[0:2M]   Wqb  -> (after QK-GEMM) part of Vb -> AO
    // ws[2M:4M]  Wkb  -> part of Vb -> AO
    // ws[0:16M]  Vb (v bf16) -> AO (attn output)
    // ws[16:32M] Qh -> (after attn) Wob
    // ws[32:48M] Kh
    // ws[48:64M] Vt
    // dout[0:16M]  Qb -> (after QK-GEMM) Wvb
    // dout[16:32M] Kb
    bf16* Qb  = (bf16*)(dob);
    bf16* Kb  = (bf16*)(dob + SZ);
    bf16* Wvb = (bf16*)(dob);
    bf16* Wqb = (bf16*)(ws);
    bf16* Wkb = (bf16*)(ws + WSZ);
    bf16* Vb  = (bf16*)(ws);
    bf16* AO  = (bf16*)(ws);
    bf16* Qh  = (bf16*)(ws + SZ);
    bf16* Wob = (bf16*)(ws + SZ);
    bf16* Kh  = (bf16*)(ws + 2 * SZ);
    bf16* Vt  = (bf16*)(ws + 3 * SZ);

    const int NQ8 = M_ROWS * D_MODEL / 8;   // 1M vec8
    const int NW8 = D_MODEL * D_MODEL / 8;  // 128K vec8
    dim3 cb(256);
    dim3 gb(256);

    // 1. convert q, k, wq, wk
    hipLaunchKernelGGL(cvt4_kernel, dim3(1024, 4), cb, 0, stream,
                       q, Qb, NQ8,  k, Kb, NQ8,  wq, Wqb, NW8,  wk, Wkb, NW8);
    // 2. Q-GEMM + K-GEMM fused (z selects)
    hipLaunchKernelGGL((gemm_bf16<0>), dim3(8, 64, 2), gb, 0, stream,
                       Qb, Wqb, bq, (void*)Qh,  Kb, Wkb, bk, (void*)Kh);
    // 3. convert v, wv
    hipLaunchKernelGGL(cvt4_kernel, dim3(1024, 2), cb, 0, stream,
                       v, Vb, NQ8,  wv, Wvb, NW8,  (const float*)0, (bf16*)0, 0,
                       (const float*)0, (bf16*)0, 0);
    // 4. V-GEMM (transposed head output)
    hipLaunchKernelGGL((gemm_bf16<1>), dim3(8, 64, 1), gb, 0, stream,
                       Vb, Wvb, bv, (void*)Vt,  Vb, Wvb, bv, (void*)Vt);
    // 5. attention
    hipLaunchKernelGGL(attn_kernel, dim3(16, 64), gb, 0, stream, Qh, Kh, Vt, AO);
    // 6. convert wo (Qh region dead)
    hipLaunchKernelGGL(cvt4_kernel, dim3(1024, 1), cb, 0, stream,
                       wo, Wob, NW8,  (const float*)0, (bf16*)0, 0,
                       (const float*)0, (bf16*)0, 0,  (const float*)0, (bf16*)0, 0);
    // 7. output GEMM -> d_out (fp32)
    hipLaunchKernelGGL((gemm_bf16<2>), dim3(8, 64, 1), gb, 0, stream,
                       AO, Wob, bo, d_out,  AO, Wob, bo, d_out);
}

// Round 4
// 420.270 us; speedup vs baseline: 1.9172x; 1.2773x over previous
//
#include <hip/hip_runtime.h>
#include <hip/hip_bf16.h>

#define D_MODEL 1024
#define N_HEAD  16
#define HD      64
#define T_SEQ   2048
#define B_SZ    4
#define M_ROWS  (B_SZ * T_SEQ)   // 8192

typedef __bf16 bf16;
typedef __bf16 bf16x4 __attribute__((ext_vector_type(4)));
typedef __bf16 bf16x8 __attribute__((ext_vector_type(8)));
typedef float  floatx4 __attribute__((ext_vector_type(4)));

__device__ __forceinline__ floatx4 fzero4() {
    floatx4 z = {0.f, 0.f, 0.f, 0.f};
    return z;
}

// async global->LDS, 16B/lane. LDS dest = wave-uniform base + lane*16.
__device__ __forceinline__ void async_ld16(const void* g, void* l) {
    __builtin_amdgcn_global_load_lds(
        (const __attribute__((address_space(1))) void*)g,
        (__attribute__((address_space(3))) void*)l,
        16, 0, 0);
}

// fused fp32 -> bf16 convert: up to 4 segments selected by blockIdx.y
__global__ __launch_bounds__(256) void cvt4_kernel(
    const float* s0, bf16* d0, int n0,
    const float* s1, bf16* d1, int n1,
    const float* s2, bf16* d2, int n2,
    const float* s3, bf16* d3, int n3)
{
    const float* src; bf16* dst; int n8;
    switch (blockIdx.y) {
        case 0:  src = s0; dst = d0; n8 = n0; break;
        case 1:  src = s1; dst = d1; n8 = n1; break;
        case 2:  src = s2; dst = d2; n8 = n2; break;
        default: src = s3; dst = d3; n8 = n3; break;
    }
    int i = blockIdx.x * blockDim.x + threadIdx.x;
    int stride = gridDim.x * blockDim.x;
    for (; i < n8; i += stride) {
        float4 a = ((const float4*)src)[2 * i];
        float4 b = ((const float4*)src)[2 * i + 1];
        bf16x8 o;
        o[0] = (bf16)a.x; o[1] = (bf16)a.y; o[2] = (bf16)a.z; o[3] = (bf16)a.w;
        o[4] = (bf16)b.x; o[5] = (bf16)b.y; o[6] = (bf16)b.z; o[7] = (bf16)b.w;
        ((bf16x8*)dst)[i] = o;
    }
}

// C[8192,1024] = A(bf16) @ W^T(bf16 [N,K]) + bias(fp32).
// LDS tiles XOR-swizzled: row r's 16B chunk c stored at pos c^(r&7).
// OMODE: 0 = bf16 head-split [B,H,T,64]; 1 = bf16 [B,H,64,T] (V); 2 = fp32 [M,N]
template <int OMODE>
__global__ __launch_bounds__(256) void gemm_bf16(
    const bf16* __restrict__ A0, const bf16* __restrict__ W0,
    const float* __restrict__ b0v, void* __restrict__ O0,
    const bf16* __restrict__ A1, const bf16* __restrict__ W1,
    const float* __restrict__ b1v, void* __restrict__ O1)
{
    __shared__ bf16 ldsA[128 * 64];
    __shared__ bf16 ldsW[128 * 64];

    const bf16* A    = blockIdx.z ? A1 : A0;
    const bf16* W    = blockIdx.z ? W1 : W0;
    const float* bias = blockIdx.z ? b1v : b0v;
    void* Out        = blockIdx.z ? O1 : O0;

    const int tid  = threadIdx.x;
    const int wave = tid >> 6, lane = tid & 63;
    const int quad = lane >> 4, l15 = lane & 15;
    const int wr = wave >> 1, wc = wave & 1;
    const int m0 = blockIdx.y * 128, n0 = blockIdx.x * 128;

    floatx4 acc[4][4];
#pragma unroll
    for (int i = 0; i < 4; ++i)
#pragma unroll
        for (int j = 0; j < 4; ++j) acc[i][j] = fzero4();

    // staging: lane -> row wave*32 + j*8 + (lane>>3); global chunk (lane&7)^((lane>>3)&7)
    const int ro = lane >> 3;
    const int gc = (lane & 7) ^ ro;
    const bf16* gA = A + (size_t)(m0 + wave * 32 + ro) * 1024 + gc * 8;
    const bf16* gW = W + (size_t)(n0 + wave * 32 + ro) * 1024 + gc * 8;

    for (int kt = 0; kt < 16; ++kt) {
        __syncthreads();
#pragma unroll
        for (int j = 0; j < 4; ++j)
            async_ld16((const void*)(gA + kt * 64 + j * 8 * 1024), &ldsA[(wave * 32 + j * 8) * 64]);
#pragma unroll
        for (int j = 0; j < 4; ++j)
            async_ld16((const void*)(gW + kt * 64 + j * 8 * 1024), &ldsW[(wave * 32 + j * 8) * 64]);
        __syncthreads();

#pragma unroll
        for (int ks = 0; ks < 2; ++ks) {
            const int pos = ((ks * 4 + quad) ^ (l15 & 7)) * 8;
            bf16x8 af[4], bw[4];
#pragma unroll
            for (int i = 0; i < 4; ++i)
                af[i] = *(const bf16x8*)(&ldsA[(wr * 64 + i * 16 + l15) * 64 + pos]);
#pragma unroll
            for (int j = 0; j < 4; ++j)
                bw[j] = *(const bf16x8*)(&ldsW[(wc * 64 + j * 16 + l15) * 64 + pos]);
#pragma unroll
            for (int i = 0; i < 4; ++i)
#pragma unroll
                for (int j = 0; j < 4; ++j)
                    acc[i][j] = __builtin_amdgcn_mfma_f32_16x16x32_bf16(af[i], bw[j], acc[i][j], 0, 0, 0);
        }
    }

#pragma unroll
    for (int i = 0; i < 4; ++i) {
#pragma unroll
        for (int j = 0; j < 4; ++j) {
#pragma unroll
            for (int r = 0; r < 4; ++r) {
                int m = m0 + wr * 64 + i * 16 + quad * 4 + r;
                int n = n0 + wc * 64 + j * 16 + l15;
                float val = acc[i][j][r] + bias[n];
                if (OMODE == 2) {
                    ((float*)Out)[(size_t)m * 1024 + n] = val;
                } else {
                    int b = m >> 11, t = m & 2047;
                    int h = n >> 6,  d = n & 63;
                    size_t addr;
                    if (OMODE == 0)
                        addr = ((size_t)(b * N_HEAD + h) * T_SEQ + t) * HD + d;
                    else
                        addr = ((size_t)(b * N_HEAD + h) * HD + d) * T_SEQ + t;
                    ((bf16*)Out)[addr] = (bf16)val;
                }
            }
        }
    }
}

// Flash-style causal attention, S^T formulation.
// Qh, Kh: [B,H,T,64] bf16.  Vt: [B,H,64,T] bf16.  AO: [B,T,D] bf16.
// grid (16 q-tiles, 64 bh), block 256 (4 waves x 32 q-rows).
// qt = 15 - blockIdx.x (longest blocks dispatch first).
// LDS 50 KB -> 3 blocks/CU.
__global__ __launch_bounds__(256, 3) void attn_kernel(
    const bf16* __restrict__ Qh, const bf16* __restrict__ Kh,
    const bf16* __restrict__ Vt, bf16* __restrict__ AO)
{
    __shared__ bf16 Ks[128 * 64];   // 16 KB, XOR-swizzled 16B chunks (c^(r&7))
    __shared__ bf16 Vts[64 * 128];  // 16 KB, XOR-swizzled (c^(d&15))
    __shared__ bf16 Ps[128 * 72];   // 18 KB, half-k P buffer (2-pass), wave-private rows

    const int tid  = threadIdx.x;
    const int wave = tid >> 6, lane = tid & 63;
    const int quad = lane >> 4, l15 = lane & 15;
    const int qt = 15 - blockIdx.x, bh = blockIdx.y;
    const size_t base = (size_t)bh * T_SEQ * HD;

    // Q fragments, B-operand layout (direct from global): lane l15 = q, k = quad*8+j
    bf16x8 qf[2][2];
    const bf16* qbase = Qh + base + (size_t)(qt * 128 + wave * 32) * HD;
#pragma unroll
    for (int ti = 0; ti < 2; ++ti)
#pragma unroll
        for (int ks = 0; ks < 2; ++ks)
            qf[ti][ks] = *(const bf16x8*)(qbase + (ti * 16 + l15) * HD + ks * 32 + quad * 8);

    const float scale2 = 0.125f * 1.44269504088896340736f;  // 1/sqrt(64) * log2(e)
    float mrow[2] = {-1e30f, -1e30f}, lrow[2] = {0.f, 0.f};
    floatx4 oacc[2][4];
#pragma unroll
    for (int ti = 0; ti < 2; ++ti)
#pragma unroll
        for (int nj = 0; nj < 4; ++nj) oacc[ti][nj] = fzero4();

    // K staging: lane -> row wave*32 + j*8 + (lane>>3); swizzled global chunk
    const int kro = lane >> 3;
    const int kgc = (lane & 7) ^ kro;
    const bf16* kg = Kh + base + (size_t)(wave * 32 + kro) * HD + kgc * 8;
    // V staging: row d = wave*16 + j*4 + (lane>>4); global chunk (lane&15)^(d&15)
    const int vrow_lo = (lane >> 4);
    const int vchunk  = (lane & 15);

    for (int kt = 0; kt <= qt; ++kt) {
        __syncthreads();   // all waves done reading Ks/Vts from prev iter
#pragma unroll
        for (int j = 0; j < 4; ++j)
            async_ld16((const void*)(kg + (size_t)(kt * 128 + j * 8) * HD),
                       &Ks[(wave * 32 + j * 8) * 64]);
#pragma unroll
        for (int j = 0; j < 4; ++j) {
            int d = wave * 16 + j * 4 + vrow_lo;
            int gcv = vchunk ^ (d & 15);
            async_ld16((const void*)(Vt + base + (size_t)d * T_SEQ + kt * 128 + gcv * 8),
                       &Vts[(wave * 16 + j * 4) * 128]);
        }
        __syncthreads();   // staging visible

        const bool diag = (kt == qt);
        const int lim = diag ? (2 * wave + 1) : 7;   // max tj with any unmasked k

        // S^T = K Q^T : A = K-frag (l15 = k-row), B = Q-frag (l15 = q)
        floatx4 sacc[2][8];
#pragma unroll
        for (int ti = 0; ti < 2; ++ti)
#pragma unroll
            for (int tj = 0; tj < 8; ++tj) sacc[ti][tj] = fzero4();
#pragma unroll
        for (int ks = 0; ks < 2; ++ks) {
            const int pos = ((ks * 4 + quad) ^ (l15 & 7)) * 8;
#pragma unroll
            for (int tj = 0; tj < 8; ++tj) {
                if (tj <= lim) {
                    bf16x8 kf = *(const bf16x8*)(&Ks[(tj * 16 + l15) * 64 + pos]);
                    sacc[0][tj] = __builtin_amdgcn_mfma_f32_16x16x32_bf16(kf, qf[0][ks], sacc[0][tj], 0, 0, 0);
                    sacc[1][tj] = __builtin_amdgcn_mfma_f32_16x16x32_bf16(kf, qf[1][ks], sacc[1][tj], 0, 0, 0);
                }
            }
        }

        // online softmax on S^T: lane owns q = l15 (per ti); k spread over tj,quad,r
#pragma unroll
        for (int ti = 0; ti < 2; ++ti) {
            const int ql = wave * 32 + ti * 16 + l15;
            float mx = -1e30f;
#pragma unroll
            for (int tj = 0; tj < 8; ++tj) {
                if (tj <= lim) {
#pragma unroll
                    for (int r = 0; r < 4; ++r) {
                        float s = sacc[ti][tj][r] * scale2;
                        if (diag && (tj * 16 + quad * 4 + r) > ql) s = -1e30f;
                        sacc[ti][tj][r] = s;
                        mx = fmaxf(mx, s);
                    }
                }
            }
            mx = fmaxf(mx, __shfl_xor(mx, 16));
            mx = fmaxf(mx, __shfl_xor(mx, 32));
            float mnew  = fmaxf(mrow[ti], mx);
            float alpha = exp2f(mrow[ti] - mnew);
            float rsum  = 0.f;
#pragma unroll
            for (int tj = 0; tj < 8; ++tj) {
                if (tj <= lim) {
#pragma unroll
                    for (int r = 0; r < 4; ++r) {
                        float p = exp2f(sacc[ti][tj][r] - mnew);
                        rsum += p;
                        sacc[ti][tj][r] = p;
                    }
                }
            }
            rsum += __shfl_xor(rsum, 16);
            rsum += __shfl_xor(rsum, 32);
            lrow[ti] = lrow[ti] * alpha + rsum;
            mrow[ti] = mnew;
#pragma unroll
            for (int r = 0; r < 4; ++r) {
                float ar = __shfl(alpha, quad * 4 + r);
#pragma unroll
                for (int nj = 0; nj < 4; ++nj)
                    oacc[ti][nj][r] *= ar;
            }
        }

        // P -> LDS and O += P V, in two k-halves (Ps is [128][72], wave-private rows)
#pragma unroll
        for (int h = 0; h < 2; ++h) {
            if (4 * h > lim) break;
#pragma unroll
            for (int ti = 0; ti < 2; ++ti) {
                const int ql = wave * 32 + ti * 16 + l15;
#pragma unroll
                for (int tjo = 0; tjo < 4; ++tjo) {
                    int tj = 4 * h + tjo;
                    if (tj <= lim) {
                        bf16x4 pv;
#pragma unroll
                        for (int r = 0; r < 4; ++r) pv[r] = (bf16)sacc[ti][tj][r];
                        *(bf16x4*)(&Ps[ql * 72 + tjo * 16 + quad * 4]) = pv;
                    }
                }
            }
#pragma unroll
            for (int ks2 = 0; ks2 < 2; ++ks2) {
                const int gks = 2 * h + ks2;
                if (diag && gks > wave) break;
                bf16x8 pf[2];
                pf[0] = *(const bf16x8*)(&Ps[(wave * 32 + l15) * 72 + ks2 * 32 + quad * 8]);
                pf[1] = *(const bf16x8*)(&Ps[(wave * 32 + 16 + l15) * 72 + ks2 * 32 + quad * 8]);
#pragma unroll
                for (int nj = 0; nj < 4; ++nj) {
                    int pos = ((gks * 4 + quad) ^ l15) * 8;
                    bf16x8 vf = *(const bf16x8*)(&Vts[(nj * 16 + l15) * 128 + pos]);
                    oacc[0][nj] = __builtin_amdgcn_mfma_f32_16x16x32_bf16(pf[0], vf, oacc[0][nj], 0, 0, 0);
                    oacc[1][nj] = __builtin_amdgcn_mfma_f32_16x16x32_bf16(pf[1], vf, oacc[1][nj], 0, 0, 0);
                }
            }
        }
    }

    // epilogue: O /= l ; O rows = quad*4+r, cols d = nj*16+l15
    const int b = bh >> 4, h = bh & 15;
#pragma unroll
    for (int ti = 0; ti < 2; ++ti) {
#pragma unroll
        for (int r = 0; r < 4; ++r) {
            float lv = __shfl(lrow[ti], quad * 4 + r);
            float rl = 1.f / lv;
            int qrow = qt * 128 + wave * 32 + ti * 16 + quad * 4 + r;
#pragma unroll
            for (int nj = 0; nj < 4; ++nj) {
                int d = nj * 16 + l15;
                AO[((size_t)(b * T_SEQ + qrow)) * D_MODEL + h * HD + d] =
                    (bf16)(oacc[ti][nj][r] * rl);
            }
        }
    }
}

extern "C" void kernel_launch(void* const* d_in, const int* in_sizes, int n_in,
                              void* d_out, int out_size, void* d_ws, size_t ws_size,
                              hipStream_t stream)
{
    const float* q  = (const float*)d_in[0];
    const float* k  = (const float*)d_in[1];
    const float* v  = (const float*)d_in[2];
    const float* wq = (const float*)d_in[3];
    const float* bq = (const float*)d_in[4];
    const float* wk = (const float*)d_in[5];
    const float* bk = (const float*)d_in[6];
    const float* wv = (const float*)d_in[7];
    const float* bv = (const float*)d_in[8];
    const float* wo = (const float*)d_in[9];
    const float* bo = (const float*)d_in[10];

    char* ws  = (char*)d_ws;
    char* dob = (char*)d_out;
    const size_t SZ  = (size_t)M_ROWS * D_MODEL * sizeof(bf16);   // 16 MiB
    const size_t WSZ = (size_t)D_MODEL * D_MODEL * sizeof(bf16);  // 2 MiB

    bf16* Qb  = (bf16*)(dob);            // dies after QK-GEMM
    bf16* Kb  = (bf16*)(dob + SZ);       // dies after QK-GEMM
    bf16* Wvb = (bf16*)(dob);            // after Qb dead
    bf16* Wqb = (bf16*)(ws);             // dies after QK-GEMM
    bf16* Wkb = (bf16*)(ws + WSZ);       // dies after QK-GEMM
    bf16* Vb  = (bf16*)(ws);             // v bf16, dies after V-GEMM
    bf16* AO  = (bf16*)(ws);             // attn out (after Vb dead)
    bf16* Qh  = (bf16*)(ws + SZ);        // dies after attn
    bf16* Wob = (bf16*)(ws + SZ);        // after Qh dead
    bf16* Kh  = (bf16*)(ws + 2 * SZ);
    bf16* Vt  = (bf16*)(ws + 3 * SZ);

    const int NQ8 = M_ROWS * D_MODEL / 8;
    const int NW8 = D_MODEL * D_MODEL / 8;
    dim3 cb(256);
    dim3 gb(256);

    hipLaunchKernelGGL(cvt4_kernel, dim3(1024, 4), cb, 0, stream,
                       q, Qb, NQ8,  k, Kb, NQ8,  wq, Wqb, NW8,  wk, Wkb, NW8);
    hipLaunchKernelGGL((gemm_bf16<0>), dim3(8, 64, 2), gb, 0, stream,
                       Qb, Wqb, bq, (void*)Qh,  Kb, Wkb, bk, (void*)Kh);
    hipLaunchKernelGGL(cvt4_kernel, dim3(1024, 2), cb, 0, stream,
                       v, Vb, NQ8,  wv, Wvb, NW8,  (const float*)0, (bf16*)0, 0,
                       (const float*)0, (bf16*)0, 0);
    hipLaunchKernelGGL((gemm_bf16<1>), dim3(8, 64, 1), gb, 0, stream,
                       Vb, Wvb, bv, (void*)Vt,  Vb, Wvb, bv, (void*)Vt);
    hipLaunchKernelGGL(attn_kernel, dim3(16, 64), gb, 0, stream, Qh, Kh, Vt, AO);
    hipLaunchKernelGGL(cvt4_kernel, dim3(1024, 1), cb, 0, stream,
                       wo, Wob, NW8,  (const float*)0, (bf16*)0, 0,
                       (const float*)0, (bf16*)0, 0,  (const float*)0, (bf16*)0, 0);
    hipLaunchKernelGGL((gemm_bf16<2>), dim3(8, 64, 1), gb, 0, stream,
                       AO, Wob, bo, d_out,  AO, Wob, bo, d_out);
}